// Round 2
// baseline (318.481 us; speedup 1.0000x reference)
//
#include <hip/hip_runtime.h>
#include <math.h>

#define BN 32
#define NPTS 2048
#define MPTS 2048
#define ITERS 5
#define LOG2E 1.44269504088896340736f

// ws layout (floats):
//  [0,192)    T   : per-batch affine 2x3 (r00,r01,tx,r10,r11,ty)
//  [192,448)  acc : per-batch 8 reduction slots (atomicAdd targets)
//  float4 idx [128, 128+BN*1024) : tp plane, (kx0,kx1,ky0,ky1) per target-pair
//      static across all iterations (written once by icp_init).
#define T_OFF   0
#define ACC_OFF 192
#define TP_F4   128

// ---------------------------------------------------------------------------
// Per-(target-pair) inner step: exponent s = qpx*kx + qpy*ky - log2e*(kx^2+ky^2) + rc
// with rc = -log2e*|st|^2  => s = -log2e * d^2 <= 0 (never overflows; the
// per-row factor 2^rc cancels exactly in ax/den).
// ---------------------------------------------------------------------------
__device__ __forceinline__ void tgt_step(float kx, float ky,
                                         float qpx, float qpy, float rc,
                                         float& den, float& ax, float& ay) {
    float a = fmaf(qpy, ky, rc);
    a = fmaf(qpx, kx, a);
    float q = kx * kx;
    q = fmaf(ky, ky, q);
    const float s = fmaf(q, -LOG2E, a);
    const float e = __builtin_amdgcn_exp2f(s);
    den += e;
    ax = fmaf(e, kx, ax);
    ay = fmaf(e, ky, ay);
}

// ---------------------------------------------------------------------------
// Heavy kernel: block = 64 rows of one batch; wave w handles M-chunk of 512.
// 16 KB LDS (2048 targets x 8 B) -> 4 blocks/CU.  Inner loop is software-
// pipelined: next 2 float4s (4 targets) load while current 4 compute.
// ---------------------------------------------------------------------------
__global__ __launch_bounds__(256, 4) void icp_rows(const float* __restrict__ source,
                                                   float* __restrict__ ws) {
    __shared__ float4 tp_s[MPTS / 2];  // 16 KB: (kx0,kx1,ky0,ky1) per pair
    const int tid  = threadIdx.x;
    const int wave = tid >> 6;
    const int lane = tid & 63;
    const int b    = blockIdx.x >> 5;   // 32 blocks per batch
    const int blk  = blockIdx.x & 31;
    const int row  = (blk << 6) | lane; // row within batch [0,2048)

    const float* T = ws + T_OFF + b * 6;
    const float r00 = T[0], r01 = T[1], tx = T[2];
    const float r10 = T[3], r11 = T[4], ty = T[5];

    const float2 sp = ((const float2*)source)[b * NPTS + row];
    const float stx = fmaf(r00, sp.x, fmaf(r01, sp.y, tx));
    const float sty = fmaf(r10, sp.x, fmaf(r11, sp.y, ty));
    const float qpx = 2.0f * LOG2E * stx;
    const float qpy = 2.0f * LOG2E * sty;
    const float rc  = -LOG2E * fmaf(stx, stx, sty * sty);

    // stage the whole batch's (kx,ky) plane: 1024 float4 / 256 threads
    const float4* tp = (const float4*)ws + TP_F4 + b * (MPTS / 2);
#pragma unroll
    for (int i = 0; i < 4; ++i) {
        const int p = (i << 8) + tid;
        tp_s[p] = tp[p];
    }
    __syncthreads();

    float d0 = 0.f, x0 = 0.f, y0 = 0.f;
    float d1 = 0.f, x1 = 0.f, y1 = 0.f;
    float d2 = 0.f, x2 = 0.f, y2 = 0.f;
    float d3 = 0.f, x3 = 0.f, y3 = 0.f;

    const float4* cp = tp_s + (wave << 8);  // this wave's 256 pairs
    float4 c0 = cp[0], c1 = cp[1];
#pragma unroll 4
    for (int p = 2; p < 256; p += 2) {
        const float4 n0 = cp[p];
        const float4 n1 = cp[p + 1];
        tgt_step(c0.x, c0.z, qpx, qpy, rc, d0, x0, y0);
        tgt_step(c0.y, c0.w, qpx, qpy, rc, d1, x1, y1);
        tgt_step(c1.x, c1.z, qpx, qpy, rc, d2, x2, y2);
        tgt_step(c1.y, c1.w, qpx, qpy, rc, d3, x3, y3);
        c0 = n0; c1 = n1;
    }
    tgt_step(c0.x, c0.z, qpx, qpy, rc, d0, x0, y0);
    tgt_step(c0.y, c0.w, qpx, qpy, rc, d1, x1, y1);
    tgt_step(c1.x, c1.z, qpx, qpy, rc, d2, x2, y2);
    tgt_step(c1.y, c1.w, qpx, qpy, rc, d3, x3, y3);

    float den = (d0 + d1) + (d2 + d3);
    float ax  = (x0 + x1) + (x2 + x3);
    float ay  = (y0 + y1) + (y2 + y3);

    // combine the 4 M-chunks across waves (reuse LDS after barrier)
    __syncthreads();
    tp_s[(wave << 6) | lane] = make_float4(den, ax, ay, 0.f);
    __syncthreads();
    if (wave == 0) {
        const float4 p0 = tp_s[lane];
        const float4 p1 = tp_s[64 + lane];
        const float4 p2 = tp_s[128 + lane];
        const float4 p3 = tp_s[192 + lane];
        den = (p0.x + p1.x) + (p2.x + p3.x);
        ax  = (p0.y + p1.y) + (p2.y + p3.y);
        ay  = (p0.z + p1.z) + (p2.z + p3.z);
        const float tcx = ax / den;
        const float tcy = ay / den;
        float v[8] = {stx, sty, tcx, tcy,
                      stx * tcx, stx * tcy, sty * tcx, sty * tcy};
#pragma unroll
        for (int off = 32; off > 0; off >>= 1) {
#pragma unroll
            for (int j = 0; j < 8; ++j) v[j] += __shfl_xor(v[j], off, 64);
        }
        if (lane == 0) {
            float* acc = ws + ACC_OFF + b * 8;
#pragma unroll
            for (int j = 0; j < 8; ++j) atomicAdd(acc + j, v[j]);
        }
    }
}

// ---------------------------------------------------------------------------
// Tiny per-batch update: closed-form 2x2 Kabsch (polar factor), compose T,
// re-zero acc. One block; thread b < 32 handles batch b. On the last
// iteration also writes the refined output.
// ---------------------------------------------------------------------------
__global__ __launch_bounds__(64) void icp_update(float* __restrict__ ws,
                                                 float* __restrict__ out,
                                                 int last) {
    const int b = threadIdx.x;
    if (b >= BN) return;
    float* acc = ws + ACC_OFF + b * 8;
    const float Ssx = acc[0], Ssy = acc[1], Stcx = acc[2], Stcy = acc[3];
    const float Sxx = acc[4], Sxy = acc[5], Syx = acc[6], Syy = acc[7];
#pragma unroll
    for (int j = 0; j < 8; ++j) acc[j] = 0.f;

    const float invN = 1.0f / (float)NPTS;
    const float csx = Ssx * invN, csy = Ssy * invN;
    const float ctx = Stcx * invN, cty = Stcy * invN;
    const float Hxx = Sxx - Ssx * ctx;
    const float Hxy = Sxy - Ssx * cty;
    const float Hyx = Syx - Ssy * ctx;
    const float Hyy = Syy - Ssy * cty;
    // A = H^T ; R_delta = polar(A): V U^T
    const float a = Hxx, bb = Hyx, cc = Hxy, d = Hyy;
    const float det = a * d - bb * cc;
    float R00, R10;
    bool refl = (det < 0.f);
    {
        const float xr = refl ? (a - d) : (a + d);
        const float yr = refl ? (bb + cc) : (cc - bb);
        const float r = fmaxf(sqrtf(xr * xr + yr * yr), 1e-30f);
        R00 = xr / r; R10 = yr / r;
    }
    const float R01 = refl ? R10 : -R10;
    const float R11 = refl ? -R00 : R00;
    const float tdx = ctx - (R00 * csx + R01 * csy);
    const float tdy = cty - (R10 * csx + R11 * csy);
    const float cD = R00, sD = R10;  // cos/sin of delta_theta (unit by constr.)
    float* Tw = ws + T_OFF + b * 6;
    const float o00 = Tw[0], o01 = Tw[1], otx = Tw[2];
    const float o10 = Tw[3], o11 = Tw[4], oty = Tw[5];
    const float n00 = cD * o00 - sD * o10;
    const float n01 = cD * o01 - sD * o11;
    const float ntx = cD * otx - sD * oty + tdx;
    const float n10 = sD * o00 + cD * o10;
    const float n11 = sD * o01 + cD * o11;
    const float nty = sD * otx + cD * oty + tdy;
    Tw[0] = n00; Tw[1] = n01; Tw[2] = ntx;
    Tw[3] = n10; Tw[4] = n11; Tw[5] = nty;
    if (last) {
        out[b * 3 + 0] = atan2f(n10, n00);
        out[b * 3 + 1] = ntx;
        out[b * 3 + 2] = nty;
    }
}

// ---------------------------------------------------------------------------
// Init: T from init_transformation, acc=0, and the static packed tp plane:
// tp[b][p] = (kx[2p], kx[2p+1], ky[2p], ky[2p+1]).
// ---------------------------------------------------------------------------
__global__ __launch_bounds__(256) void icp_init(const float* __restrict__ target,
                                                const float* __restrict__ init_t,
                                                float* __restrict__ ws) {
    const int b = blockIdx.x;
    const int tid = threadIdx.x;
    if (tid == 0) {
        const float th = init_t[b * 3 + 0];
        const float c = cosf(th), s = sinf(th);
        float* Tw = ws + T_OFF + b * 6;
        Tw[0] = c;  Tw[1] = -s; Tw[2] = init_t[b * 3 + 1];
        Tw[3] = s;  Tw[4] = c;  Tw[5] = init_t[b * 3 + 2];
        float* acc = ws + ACC_OFF + b * 8;
#pragma unroll
        for (int j = 0; j < 8; ++j) acc[j] = 0.f;
    }
    float4* tp = (float4*)ws + TP_F4 + b * (MPTS / 2);
#pragma unroll
    for (int i = 0; i < 4; ++i) {
        const int p = (i << 8) + tid;                 // pair index [0,1024)
        const float4 kk = ((const float4*)target)[b * (MPTS / 2) + p];
        // kk = (x_{2p}, y_{2p}, x_{2p+1}, y_{2p+1})
        tp[p] = make_float4(kk.x, kk.z, kk.y, kk.w);  // (kx0,kx1,ky0,ky1)
    }
}

extern "C" void kernel_launch(void* const* d_in, const int* in_sizes, int n_in,
                              void* d_out, int out_size, void* d_ws, size_t ws_size,
                              hipStream_t stream) {
    const float* source = (const float*)d_in[0];
    const float* target = (const float*)d_in[1];
    const float* initt  = (const float*)d_in[2];
    float* out = (float*)d_out;
    float* ws  = (float*)d_ws;

    icp_init<<<BN, 256, 0, stream>>>(target, initt, ws);
    for (int it = 0; it < ITERS; ++it) {
        icp_rows<<<BN * 32, 256, 0, stream>>>(source, ws);
        icp_update<<<1, 64, 0, stream>>>(ws, out, it == ITERS - 1);
    }
}

// Round 3
// 241.801 us; speedup vs baseline: 1.3171x; 1.3171x over previous
//
#include <hip/hip_runtime.h>
#include <math.h>

#define BN 32
#define NPTS 2048
#define MPTS 2048
#define ITERS 5
#define LOG2E 1.44269504088896340736f

typedef float v2f __attribute__((ext_vector_type(2)));

// ws layout (floats):
//  [0,192)      T   : per-batch affine 2x3 (r00,r01,tx,r10,r11,ty)
//  [192,448)    acc : per-batch 8 reduction slots (atomicAdd targets)
//  [512, 512+BN*4096)          planeA : per-pair float4 (kx0,kx1,ky0,ky1), static
//  [512+BN*4096, +BN*2048)     planeB : per-pair float2 (bm0,bm1), bm=-log2e*|t|^2, static
#define T_OFF   0
#define ACC_OFF 192
#define PA_OFF  512
#define PB_OFF  (512 + BN * 4096)

// per-2-targets step; exponent s = qpx*kx + qpy*ky + bm + rc = -log2e*d^2 <= 0
__device__ __forceinline__ void step2(const float4 c, const float2 bm,
                                      const v2f qpx2, const v2f qpy2, const v2f rc2,
                                      v2f& den, v2f& ax, v2f& ay) {
    const v2f kx = {c.x, c.y};
    const v2f ky = {c.z, c.w};
    v2f t = v2f{bm.x, bm.y} + rc2;
    t = __builtin_elementwise_fma(ky, qpy2, t);
    t = __builtin_elementwise_fma(kx, qpx2, t);
    const v2f e = {__builtin_amdgcn_exp2f(t.x), __builtin_amdgcn_exp2f(t.y)};
    den = den + e;
    ax = __builtin_elementwise_fma(e, kx, ax);
    ay = __builtin_elementwise_fma(e, ky, ay);
}

// ---------------------------------------------------------------------------
// Heavy kernel: block = 64 rows of one batch, 512 threads = 8 waves; wave w
// scans M-chunk of 256 targets (128 pairs). 24 KB LDS -> 4 blocks/CU by grid,
// VGPR capped at 64 -> 8 waves/SIMD resident.
// ---------------------------------------------------------------------------
__global__ __launch_bounds__(512, 8) void icp_rows(const float* __restrict__ source,
                                                   float* __restrict__ ws) {
    __shared__ float4 pA[MPTS / 2];  // 16 KB
    __shared__ float2 pB[MPTS / 2];  //  8 KB
    const int tid  = threadIdx.x;
    const int wave = tid >> 6;          // 0..7: M-chunk
    const int lane = tid & 63;
    const int b    = blockIdx.x >> 5;   // 32 blocks per batch
    const int blk  = blockIdx.x & 31;
    const int row  = (blk << 6) | lane; // row within batch [0,2048)

    // stage the whole batch's planes (coalesced; wave-parallel)
    const float4* gA  = (const float4*)(ws + PA_OFF) + b * (MPTS / 2);
    const float4* gB4 = (const float4*)(ws + PB_OFF) + b * (MPTS / 4);
    pA[tid]       = gA[tid];
    pA[tid + 512] = gA[tid + 512];
    ((float4*)pB)[tid] = gB4[tid];

    const float* T = ws + T_OFF + b * 6;
    const float r00 = T[0], r01 = T[1], tx = T[2];
    const float r10 = T[3], r11 = T[4], ty = T[5];
    const float2 sp = ((const float2*)source)[b * NPTS + row];
    const float stx = fmaf(r00, sp.x, fmaf(r01, sp.y, tx));
    const float sty = fmaf(r10, sp.x, fmaf(r11, sp.y, ty));
    const float qpx = 2.0f * LOG2E * stx;
    const float qpy = 2.0f * LOG2E * sty;
    const float rc  = -LOG2E * fmaf(stx, stx, sty * sty);
    const v2f qpx2 = {qpx, qpx};
    const v2f qpy2 = {qpy, qpy};
    const v2f rc2  = {rc, rc};

    __syncthreads();

    v2f den0 = {0.f, 0.f}, ax0 = {0.f, 0.f}, ay0 = {0.f, 0.f};
    v2f den1 = {0.f, 0.f}, ax1 = {0.f, 0.f}, ay1 = {0.f, 0.f};

    const float4* cpA = pA + (wave << 7);  // this wave's 128 pairs
    const float2* cpB = pB + (wave << 7);
    float4 a0 = cpA[0], a1 = cpA[1];
    float2 b0 = cpB[0], b1 = cpB[1];
#pragma unroll 4
    for (int p = 2; p < 128; p += 2) {
        const float4 na0 = cpA[p], na1 = cpA[p + 1];
        const float2 nb0 = cpB[p], nb1 = cpB[p + 1];
        step2(a0, b0, qpx2, qpy2, rc2, den0, ax0, ay0);
        step2(a1, b1, qpx2, qpy2, rc2, den1, ax1, ay1);
        a0 = na0; a1 = na1; b0 = nb0; b1 = nb1;
    }
    step2(a0, b0, qpx2, qpy2, rc2, den0, ax0, ay0);
    step2(a1, b1, qpx2, qpy2, rc2, den1, ax1, ay1);

    const float den = (den0.x + den0.y) + (den1.x + den1.y);
    const float ax  = (ax0.x + ax0.y) + (ax1.x + ax1.y);
    const float ay  = (ay0.x + ay0.y) + (ay1.x + ay1.y);

    // combine the 8 M-chunks across waves (reuse pA after barrier)
    __syncthreads();
    ((float4*)pA)[(wave << 6) | lane] = make_float4(den, ax, ay, 0.f);
    __syncthreads();
    if (wave == 0) {
        float dsum = 0.f, xsum = 0.f, ysum = 0.f;
#pragma unroll
        for (int w = 0; w < 8; ++w) {
            const float4 p = ((const float4*)pA)[(w << 6) | lane];
            dsum += p.x; xsum += p.y; ysum += p.z;
        }
        const float tcx = xsum / dsum;
        const float tcy = ysum / dsum;
        float v[8] = {stx, sty, tcx, tcy,
                      stx * tcx, stx * tcy, sty * tcx, sty * tcy};
#pragma unroll
        for (int off = 32; off > 0; off >>= 1) {
#pragma unroll
            for (int j = 0; j < 8; ++j) v[j] += __shfl_xor(v[j], off, 64);
        }
        if (lane == 0) {
            float* acc = ws + ACC_OFF + b * 8;
#pragma unroll
            for (int j = 0; j < 8; ++j) atomicAdd(acc + j, v[j]);
        }
    }
}

// ---------------------------------------------------------------------------
// Tiny per-batch update: closed-form 2x2 Kabsch (polar factor), compose T,
// re-zero acc; writes output on the last iteration.
// ---------------------------------------------------------------------------
__global__ __launch_bounds__(64) void icp_update(float* __restrict__ ws,
                                                 float* __restrict__ out,
                                                 int last) {
    const int b = threadIdx.x;
    if (b >= BN) return;
    float* acc = ws + ACC_OFF + b * 8;
    const float Ssx = acc[0], Ssy = acc[1], Stcx = acc[2], Stcy = acc[3];
    const float Sxx = acc[4], Sxy = acc[5], Syx = acc[6], Syy = acc[7];
#pragma unroll
    for (int j = 0; j < 8; ++j) acc[j] = 0.f;

    const float invN = 1.0f / (float)NPTS;
    const float csx = Ssx * invN, csy = Ssy * invN;
    const float ctx = Stcx * invN, cty = Stcy * invN;
    const float Hxx = Sxx - Ssx * ctx;
    const float Hxy = Sxy - Ssx * cty;
    const float Hyx = Syx - Ssy * ctx;
    const float Hyy = Syy - Ssy * cty;
    // A = H^T ; R_delta = polar(A) = V U^T
    const float a = Hxx, bb = Hyx, cc = Hxy, d = Hyy;
    const float det = a * d - bb * cc;
    const bool refl = (det < 0.f);
    const float xr = refl ? (a - d) : (a + d);
    const float yr = refl ? (bb + cc) : (cc - bb);
    const float r = fmaxf(sqrtf(xr * xr + yr * yr), 1e-30f);
    const float R00 = xr / r, R10 = yr / r;
    const float R01 = refl ? R10 : -R10;
    const float R11 = refl ? -R00 : R00;
    const float tdx = ctx - (R00 * csx + R01 * csy);
    const float tdy = cty - (R10 * csx + R11 * csy);
    const float cD = R00, sD = R10;
    float* Tw = ws + T_OFF + b * 6;
    const float o00 = Tw[0], o01 = Tw[1], otx = Tw[2];
    const float o10 = Tw[3], o11 = Tw[4], oty = Tw[5];
    const float n00 = cD * o00 - sD * o10;
    const float n01 = cD * o01 - sD * o11;
    const float ntx = cD * otx - sD * oty + tdx;
    const float n10 = sD * o00 + cD * o10;
    const float n11 = sD * o01 + cD * o11;
    const float nty = sD * otx + cD * oty + tdy;
    Tw[0] = n00; Tw[1] = n01; Tw[2] = ntx;
    Tw[3] = n10; Tw[4] = n11; Tw[5] = nty;
    if (last) {
        out[b * 3 + 0] = atan2f(n10, n00);
        out[b * 3 + 1] = ntx;
        out[b * 3 + 2] = nty;
    }
}

// ---------------------------------------------------------------------------
// Init: T from init_transformation, acc=0, static packed target planes.
// planeA[p] = (x_{2p}, x_{2p+1}, y_{2p}, y_{2p+1});  planeB[p] = -log2e*|t|^2 pair.
// ---------------------------------------------------------------------------
__global__ __launch_bounds__(256) void icp_init(const float* __restrict__ target,
                                                const float* __restrict__ init_t,
                                                float* __restrict__ ws) {
    const int b = blockIdx.x;
    const int tid = threadIdx.x;
    if (tid == 0) {
        const float th = init_t[b * 3 + 0];
        const float c = cosf(th), s = sinf(th);
        float* Tw = ws + T_OFF + b * 6;
        Tw[0] = c;  Tw[1] = -s; Tw[2] = init_t[b * 3 + 1];
        Tw[3] = s;  Tw[4] = c;  Tw[5] = init_t[b * 3 + 2];
        float* acc = ws + ACC_OFF + b * 8;
#pragma unroll
        for (int j = 0; j < 8; ++j) acc[j] = 0.f;
    }
    float4* gA = (float4*)(ws + PA_OFF) + b * (MPTS / 2);
    float2* gB = (float2*)(ws + PB_OFF) + b * (MPTS / 2);
#pragma unroll
    for (int i = 0; i < 4; ++i) {
        const int p = (i << 8) + tid;  // pair index [0,1024)
        const float4 kk = ((const float4*)target)[b * (MPTS / 2) + p];
        // kk = (x0,y0,x1,y1) for targets 2p,2p+1
        gA[p] = make_float4(kk.x, kk.z, kk.y, kk.w);
        gB[p] = make_float2(-LOG2E * fmaf(kk.x, kk.x, kk.y * kk.y),
                            -LOG2E * fmaf(kk.z, kk.z, kk.w * kk.w));
    }
}

extern "C" void kernel_launch(void* const* d_in, const int* in_sizes, int n_in,
                              void* d_out, int out_size, void* d_ws, size_t ws_size,
                              hipStream_t stream) {
    const float* source = (const float*)d_in[0];
    const float* target = (const float*)d_in[1];
    const float* initt  = (const float*)d_in[2];
    float* out = (float*)d_out;
    float* ws  = (float*)d_ws;

    icp_init<<<BN, 256, 0, stream>>>(target, initt, ws);
    for (int it = 0; it < ITERS; ++it) {
        icp_rows<<<BN * 32, 512, 0, stream>>>(source, ws);
        icp_update<<<1, 64, 0, stream>>>(ws, out, it == ITERS - 1);
    }
}